// Round 4
// baseline (556.126 us; speedup 1.0000x reference)
//
#include <hip/hip_runtime.h>

typedef __bf16 bf16x8 __attribute__((ext_vector_type(8)));
typedef __bf16 bf16x4 __attribute__((ext_vector_type(4)));
typedef float f32x4 __attribute__((ext_vector_type(4)));

#define S_BARRIER() asm volatile("s_barrier" ::: "memory")
#define WAITCNT_VM(n) asm volatile("s_waitcnt vmcnt(" #n ")" ::: "memory")
#define WAITCNT_VM0() asm volatile("s_waitcnt vmcnt(0)" ::: "memory")
#define WAITCNT_LGKM0() asm volatile("s_waitcnt lgkmcnt(0)" ::: "memory")

// ---------------------------------------------------------------------------
// Prep: weight transposes (blocks [0,ntiles)) + LN row stats (mu, rstd)
// (blocks [ntiles, ntiles+M/4), one wave per row).  No hn materialization.
// ---------------------------------------------------------------------------
__global__ __launch_bounds__(256) void prep_stats_kernel(
    const float* __restrict__ Wd, __bf16* __restrict__ Wtd,
    const float* __restrict__ Wu, __bf16* __restrict__ Wtu,
    const float* __restrict__ x, float2* __restrict__ stats,
    int D, int Db, int ntiles) {
    if ((int)blockIdx.x < ntiles) {
        const float* W;
        __bf16* Wt;
        int K, N, tile;
        const int ntile_d = (Db / 32) * (D / 32);
        if ((int)blockIdx.x < ntile_d) {
            W = Wd; Wt = Wtd; K = D; N = Db; tile = blockIdx.x;
        } else {
            W = Wu; Wt = Wtu; K = Db; N = D; tile = blockIdx.x - ntile_d;
        }
        const int tn = tile % (N / 32), tk = tile / (N / 32);
        const int n0 = tn * 32, k0 = tk * 32;
        __shared__ float t[32][33];
        const int c = threadIdx.x & 31, r0 = threadIdx.x >> 5;
#pragma unroll
        for (int r = r0; r < 32; r += 8)
            t[r][c] = W[(size_t)(k0 + r) * N + n0 + c];
        __syncthreads();
#pragma unroll
        for (int r = r0; r < 32; r += 8)
            Wt[(size_t)(n0 + r) * K + k0 + c] = (__bf16)t[c][r];
        return;
    }
    // ---- LN stats: 4 rows per block, 1 wave per row ----
    const int wid = threadIdx.x >> 6, lane = threadIdx.x & 63;
    const size_t row = (size_t)(blockIdx.x - ntiles) * 4 + wid;
    const float4* xr = (const float4*)(x + row * (size_t)D);
    const int nv = D >> 2;
    float s = 0.f, ss = 0.f;
    for (int i = lane; i < nv; i += 64) {
        float4 v = xr[i];
        s += v.x + v.y + v.z + v.w;
        ss += v.x * v.x + v.y * v.y + v.z * v.z + v.w * v.w;
    }
    for (int o = 32; o > 0; o >>= 1) {
        s += __shfl_down(s, o);
        ss += __shfl_down(ss, o);
    }
    if (lane == 0) {
        float mu = s / (float)D;
        float var = ss / (float)D - mu * mu;
        stats[row] = make_float2(mu, rsqrtf(var + 1e-5f));
    }
}

// ---------------------------------------------------------------------------
// GEMM1 with fused LayerNorm on the A operand.
// A-tile: plain fp32 loads -> normalize (mu,rstd,gamma,beta) -> bf16 ->
//         ds_write_b128 into LDS (layout Ads[row*32+k], matches B DMA layout).
// B-tile: Wtd [N][K] bf16 via global_load_lds width=16.
// 3 LDS buffers; tile t staged at iter t-2, certified at end of iter t-1:
//   cross-region drain correctness: gamma/beta(t) loads live in region t-1
//   (after the end-of-(t-2) s_barrier), so the compiler's wait for them
//   before cvt also drains B_DMA(t) (issued in region t-2).  ds_writes are
//   certified by lgkmcnt(0)+s_barrier.
// Epilogue: z = silu(acc + bias) -> bf16 (swapped-D layout, bf16x4 stores).
// ---------------------------------------------------------------------------
__global__ __launch_bounds__(256) void gemm1_ln(
    const float* __restrict__ H, const float2* __restrict__ stats,
    const float* __restrict__ gamma, const float* __restrict__ beta,
    const __bf16* __restrict__ Bt, const float* __restrict__ bias,
    __bf16* __restrict__ Z, int M, int N, int K) {
    constexpr int BM = 128, BN = 128, BK = 32;
    __shared__ __align__(16) __bf16 Ads[3][BM * BK];
    __shared__ __align__(16) __bf16 Bds[3][BN * BK];

    const int tid = threadIdx.x, wave = tid >> 6, lane = tid & 63;
    const int row0 = blockIdx.y * BM, col0 = blockIdx.x * BN;
    const int wr = wave >> 1, wc = wave & 1;
    f32x4 acc[4][4] = {};

    const __bf16* Bg = Bt + (size_t)col0 * K;
    const int lrow = lane >> 2, lk = (lane & 3) * 8;

    const int arow = tid >> 1, akoff = (tid & 1) * 16;
    const float* Arow = H + (size_t)(row0 + arow) * K;
    const float2 st = stats[row0 + arow];
    const float mu = st.x, rstd = st.y;
    float4 R[2][4], g4[4], b4[4];

    auto stageB = [&](int k0, int b) {
#pragma unroll
        for (int p = 0; p < 2; ++p) {
            const int r = wave * 32 + p * 16;
            __builtin_amdgcn_global_load_lds(
                (__attribute__((address_space(1))) void*)(Bg + (size_t)(r + lrow) * K + k0 + lk),
                (__attribute__((address_space(3))) void*)(&Bds[b][r * BK]),
                16, 0, 0);
        }
    };
    auto loadA = [&](int k0, int rb) {
#pragma unroll
        for (int i = 0; i < 4; ++i)
            R[rb][i] = *(const float4*)(Arow + k0 + akoff + i * 4);
    };
    auto loadGB = [&](int k0) {
#pragma unroll
        for (int i = 0; i < 4; ++i) {
            g4[i] = *(const float4*)(gamma + k0 + akoff + i * 4);
            b4[i] = *(const float4*)(beta + k0 + akoff + i * 4);
        }
    };
    auto cvtWrite = [&](int rb, int b) {
        __bf16 tmp[16];
#pragma unroll
        for (int i = 0; i < 4; ++i) {
            float4 a = R[rb][i], g = g4[i], bb = b4[i];
            tmp[i * 4 + 0] = (__bf16)((a.x - mu) * rstd * g.x + bb.x);
            tmp[i * 4 + 1] = (__bf16)((a.y - mu) * rstd * g.y + bb.y);
            tmp[i * 4 + 2] = (__bf16)((a.z - mu) * rstd * g.z + bb.z);
            tmp[i * 4 + 3] = (__bf16)((a.w - mu) * rstd * g.w + bb.w);
        }
        *(bf16x8*)(&Ads[b][arow * BK + akoff]) = *(bf16x8*)(tmp);
        *(bf16x8*)(&Ads[b][arow * BK + akoff + 8]) = *(bf16x8*)(tmp + 8);
    };

    const int nk = K / BK;
    // Prologue: tile0 fully staged+drained; tile1 in flight across barrier.
    stageB(0, 0);
    loadA(0, 0);
    loadGB(0);
    WAITCNT_VM0();
    stageB(BK, 1);
    loadA(BK, 1);
    cvtWrite(0, 0);
    WAITCNT_LGKM0();
    S_BARRIER();

    for (int it = 0; it < nk; ++it) {
        const int cur = it % 3;
        if (it + 1 < nk) loadGB((it + 1) * BK);
        if (it + 2 < nk) {
            stageB((it + 2) * BK, (it + 2) % 3);
            loadA((it + 2) * BK, it & 1);
        }
        bf16x8 afW[4], bfA[4];
#pragma unroll
        for (int j = 0; j < 4; ++j)
            afW[j] = *(const bf16x8*)(&Bds[cur][(wc * 64 + j * 16 + (lane & 15)) * BK + (lane >> 4) * 8]);
#pragma unroll
        for (int i = 0; i < 4; ++i)
            bfA[i] = *(const bf16x8*)(&Ads[cur][(wr * 64 + i * 16 + (lane & 15)) * BK + (lane >> 4) * 8]);
#pragma unroll
        for (int i = 0; i < 4; ++i)
#pragma unroll
            for (int j = 0; j < 4; ++j)
                acc[i][j] = __builtin_amdgcn_mfma_f32_16x16x32_bf16(afW[j], bfA[i],
                                                                    acc[i][j], 0, 0, 0);
        if (it + 1 < nk) cvtWrite((it + 1) & 1, (it + 1) % 3);
        WAITCNT_LGKM0();
        S_BARRIER();
    }

    // Epilogue: z = silu(acc+bias), swapped-D layout
    const int c = lane & 15, q = lane >> 4;
#pragma unroll
    for (int i = 0; i < 4; ++i) {
        const int rowg = row0 + wr * 64 + i * 16 + c;
#pragma unroll
        for (int j = 0; j < 4; ++j) {
            const int colb = col0 + wc * 64 + j * 16 + q * 4;
            const float4 bv = *(const float4*)(bias + colb);
            float v0 = acc[i][j][0] + bv.x;
            float v1 = acc[i][j][1] + bv.y;
            float v2 = acc[i][j][2] + bv.z;
            float v3 = acc[i][j][3] + bv.w;
            bf16x4 o;
            o[0] = (__bf16)(v0 / (1.f + __expf(-v0)));
            o[1] = (__bf16)(v1 / (1.f + __expf(-v1)));
            o[2] = (__bf16)(v2 / (1.f + __expf(-v2)));
            o[3] = (__bf16)(v3 / (1.f + __expf(-v3)));
            *(bf16x4*)(Z + (size_t)rowg * N + colb) = o;
        }
    }
}

// ---------------------------------------------------------------------------
// GEMM2 + residual.  A = z bf16 via DMA, B = Wtu via DMA, 3 LDS buffers,
// 2-iteration-deep pipeline: tile t staged at iter t-2, drained by vmcnt(4)
// at end of iter t-1 (leaves only region-t's 4 DMAs in flight).
// Epilogue: out = hid + alpha*(acc + bias - hid), fp32 float4.
// ---------------------------------------------------------------------------
__global__ __launch_bounds__(256) void gemm2_res(
    const __bf16* __restrict__ A, const __bf16* __restrict__ Bt,
    const float* __restrict__ bias, const float* __restrict__ hid,
    const float* __restrict__ alpha_p, float* __restrict__ out,
    int M, int N, int K) {
    constexpr int BM = 128, BN = 128, BK = 32;
    __shared__ __align__(16) __bf16 Ads[3][BM * BK];
    __shared__ __align__(16) __bf16 Bds[3][BN * BK];

    const int tid = threadIdx.x, wave = tid >> 6, lane = tid & 63;
    const int row0 = blockIdx.y * BM, col0 = blockIdx.x * BN;
    const int wr = wave >> 1, wc = wave & 1;
    f32x4 acc[4][4] = {};

    const __bf16* Ag = A + (size_t)row0 * K;
    const __bf16* Bg = Bt + (size_t)col0 * K;
    const int lrow = lane >> 2, lk = (lane & 3) * 8;

    auto stage = [&](int k0, int b) {
#pragma unroll
        for (int p = 0; p < 2; ++p) {
            const int r = wave * 32 + p * 16;
            __builtin_amdgcn_global_load_lds(
                (__attribute__((address_space(1))) void*)(Ag + (size_t)(r + lrow) * K + k0 + lk),
                (__attribute__((address_space(3))) void*)(&Ads[b][r * BK]),
                16, 0, 0);
            __builtin_amdgcn_global_load_lds(
                (__attribute__((address_space(1))) void*)(Bg + (size_t)(r + lrow) * K + k0 + lk),
                (__attribute__((address_space(3))) void*)(&Bds[b][r * BK]),
                16, 0, 0);
        }
    };

    const int nk = K / BK;
    stage(0, 0);
    stage(BK, 1);
    WAITCNT_VM(4);  // drain tile0's 4 DMAs; tile1 stays in flight
    S_BARRIER();

    for (int it = 0; it < nk; ++it) {
        const int cur = it % 3;
        if (it + 2 < nk) stage((it + 2) * BK, (it + 2) % 3);

        bf16x8 afW[4], bfA[4];
#pragma unroll
        for (int j = 0; j < 4; ++j)
            afW[j] = *(const bf16x8*)(&Bds[cur][(wc * 64 + j * 16 + (lane & 15)) * BK + (lane >> 4) * 8]);
#pragma unroll
        for (int i = 0; i < 4; ++i)
            bfA[i] = *(const bf16x8*)(&Ads[cur][(wr * 64 + i * 16 + (lane & 15)) * BK + (lane >> 4) * 8]);
#pragma unroll
        for (int i = 0; i < 4; ++i)
#pragma unroll
            for (int j = 0; j < 4; ++j)
                acc[i][j] = __builtin_amdgcn_mfma_f32_16x16x32_bf16(afW[j], bfA[i],
                                                                    acc[i][j], 0, 0, 0);
        // Drain tile (it+1)'s DMAs (region it-1): leave only region-it's 4.
        if (it + 2 < nk) { WAITCNT_VM(4); } else { WAITCNT_VM0(); }
        WAITCNT_LGKM0();
        S_BARRIER();
    }

    const float alpha = *alpha_p;
    const int c = lane & 15, q = lane >> 4;
#pragma unroll
    for (int i = 0; i < 4; ++i) {
        const int rowg = row0 + wr * 64 + i * 16 + c;
#pragma unroll
        for (int j = 0; j < 4; ++j) {
            const int colb = col0 + wc * 64 + j * 16 + q * 4;
            const float4 bv = *(const float4*)(bias + colb);
            const size_t idx = (size_t)rowg * N + colb;
            const float4 h = *(const float4*)(hid + idx);
            float4 o;
            o.x = h.x + alpha * (acc[i][j][0] + bv.x - h.x);
            o.y = h.y + alpha * (acc[i][j][1] + bv.y - h.y);
            o.z = h.z + alpha * (acc[i][j][2] + bv.z - h.z);
            o.w = h.w + alpha * (acc[i][j][3] + bv.w - h.w);
            *(float4*)(out + idx) = o;
        }
    }
}

// ---------------------------------------------------------------------------
// Launch
// ---------------------------------------------------------------------------
extern "C" void kernel_launch(void* const* d_in, const int* in_sizes, int n_in,
                              void* d_out, int out_size, void* d_ws, size_t ws_size,
                              hipStream_t stream) {
    const float* hidden = (const float*)d_in[0];
    const float* ln_gamma = (const float*)d_in[1];
    const float* ln_beta = (const float*)d_in[2];
    const float* W_down = (const float*)d_in[3];
    const float* b_down = (const float*)d_in[4];
    const float* W_up = (const float*)d_in[5];
    const float* b_up = (const float*)d_in[6];
    const float* alpha = (const float*)d_in[7];
    float* out = (float*)d_out;

    const int D = in_sizes[2];      // 2048
    const int Db = in_sizes[4];     // 512
    const int M = in_sizes[0] / D;  // 16384

    char* w = (char*)d_ws;
    __bf16* z = (__bf16*)w;     w += (size_t)M * Db * sizeof(__bf16);
    __bf16* Wtd = (__bf16*)w;   w += (size_t)D * Db * sizeof(__bf16);   // [Db][D]
    __bf16* Wtu = (__bf16*)w;   w += (size_t)Db * D * sizeof(__bf16);   // [D][Db]
    float2* stats = (float2*)w; w += (size_t)M * sizeof(float2);

    const int ntiles = 2 * (D / 32) * (Db / 32);
    prep_stats_kernel<<<ntiles + M / 4, 256, 0, stream>>>(
        W_down, Wtd, W_up, Wtu, hidden, stats, D, Db, ntiles);

    gemm1_ln<<<dim3(Db / 128, M / 128), 256, 0, stream>>>(
        hidden, stats, ln_gamma, ln_beta, Wtd, b_down, z, M, Db, D);

    gemm2_res<<<dim3(D / 128, M / 128), 256, 0, stream>>>(
        z, Wtu, b_up, hidden, alpha, out, M, D, Db);
}